// Round 1
// baseline (1918.354 us; speedup 1.0000x reference)
//
#include <hip/hip_runtime.h>

#define NN   50000
#define ERAW 800000
#define ETOT 850000

__device__ __forceinline__ void edge_sd(const int* __restrict__ ei, int e, int& s, int& d) {
    if (e < ERAW) { s = ei[e]; d = ei[ERAW + e]; }
    else { int n = e - ERAW; s = n; d = n; }
}

// h = x @ W (per-node), plus attention coefficients al_s, al_d
template<int F_IN, int H, int C>
__global__ void gemm_att_kernel(const float* __restrict__ x, const float* __restrict__ W,
                                const float* __restrict__ asrc, const float* __restrict__ adst,
                                float* __restrict__ h, float* __restrict__ als,
                                float* __restrict__ ald)
{
    constexpr int HC = H * C;
    int n = blockIdx.x;
    __shared__ float xs[F_IN];
    __shared__ float hs[HC];
    int t = threadIdx.x;
    for (int k = t; k < F_IN; k += blockDim.x) xs[k] = x[(size_t)n * F_IN + k];
    __syncthreads();
    if (t < HC) {
        float acc = 0.f;
        #pragma unroll 8
        for (int k = 0; k < F_IN; ++k) acc = fmaf(xs[k], W[k * HC + t], acc);
        h[(size_t)n * HC + t] = acc;
        hs[t] = acc;
    }
    __syncthreads();
    if (t < H) {
        float s1 = 0.f, s2 = 0.f;
        #pragma unroll
        for (int c = 0; c < C; ++c) {
            float v = hs[t * C + c];
            s1 = fmaf(v, asrc[t * C + c], s1);
            s2 = fmaf(v, adst[t * C + c], s2);
        }
        als[n * H + t] = s1;
        ald[n * H + t] = s2;
    }
}

// leaky_relu(al_s[src]+al_d[dst]) -> ebuf ; segment max via monotonic-uint atomicMax
template<int H>
__global__ void att_logit_max(const int* __restrict__ ei, const float* __restrict__ als,
                              const float* __restrict__ ald, float* __restrict__ ebuf,
                              unsigned* __restrict__ maxb)
{
    int e = blockIdx.x * blockDim.x + threadIdx.x;
    if (e >= ETOT) return;
    int s, d; edge_sd(ei, e, s, d);
    #pragma unroll
    for (int hh = 0; hh < H; ++hh) {
        float v = als[s * H + hh] + ald[d * H + hh];
        v = v > 0.f ? v : 0.2f * v;
        ebuf[(size_t)e * H + hh] = v;
        unsigned b = __float_as_uint(v);
        unsigned key = (b & 0x80000000u) ? ~b : (b | 0x80000000u);
        atomicMax(&maxb[d * H + hh], key);
    }
}

// ex = exp(e - max[dst]); store back; accumulate denominator
template<int H>
__global__ void att_exp_sum(const int* __restrict__ ei, float* __restrict__ ebuf,
                            const unsigned* __restrict__ maxb, float* __restrict__ denom)
{
    int idx = blockIdx.x * blockDim.x + threadIdx.x;
    if (idx >= ETOT * H) return;
    int e = idx / H, hh = idx - e * H;
    int s, d; edge_sd(ei, e, s, d);
    (void)s;
    unsigned key = maxb[d * H + hh];
    unsigned b = (key & 0x80000000u) ? (key ^ 0x80000000u) : ~key;
    float m = __uint_as_float(b);
    float ex = __expf(ebuf[idx] - m);
    ebuf[idx] = ex;
    atomicAdd(&denom[d * H + hh], ex);
}

// acc[dst] += h[src] * ex   (numerator; normalize by denom in finalize)
template<int H, int C>
__global__ void aggregate_kernel(const int* __restrict__ ei, const float* __restrict__ hbuf,
                                 const float* __restrict__ ebuf, float* __restrict__ acc)
{
    constexpr int HC = H * C;
    int t = blockIdx.x * blockDim.x + threadIdx.x;
    int e = t / HC;
    if (e >= ETOT) return;
    int j = t - e * HC;
    int s, d; edge_sd(ei, e, s, d);
    float alpha = ebuf[(size_t)e * H + j / C];
    atomicAdd(&acc[(size_t)d * HC + j], hbuf[(size_t)s * HC + j] * alpha);
}

// out = acc/denom + bias (+ReLU)
template<int H, int C, bool RELU>
__global__ void finalize_kernel(const float* __restrict__ acc, const float* __restrict__ denom,
                                const float* __restrict__ bias, float* __restrict__ out)
{
    constexpr int HC = H * C;
    int t = blockIdx.x * blockDim.x + threadIdx.x;
    if (t >= NN * HC) return;
    int n = t / HC;
    int j = t - n * HC;
    float v = acc[t] / (denom[n * H + j / C] + 1e-16f) + bias[j];
    if (RELU) v = fmaxf(v, 0.f);
    out[t] = v;
}

extern "C" void kernel_launch(void* const* d_in, const int* in_sizes, int n_in,
                              void* d_out, int out_size, void* d_ws, size_t ws_size,
                              hipStream_t stream) {
    const float* x   = (const float*)d_in[0];
    const int*   ei  = (const int*)d_in[1];
    const float* W0  = (const float*)d_in[2];
    const float* as0 = (const float*)d_in[3];
    const float* ad0 = (const float*)d_in[4];
    const float* b0  = (const float*)d_in[5];
    const float* W1  = (const float*)d_in[6];
    const float* as1 = (const float*)d_in[7];
    const float* ad1 = (const float*)d_in[8];
    const float* b1  = (const float*)d_in[9];
    const float* W2  = (const float*)d_in[10];
    const float* as2 = (const float*)d_in[11];
    const float* ad2 = (const float*)d_in[12];
    const float* b2  = (const float*)d_in[13];
    float* out = (float*)d_out;

    float* ws = (float*)d_ws;
    size_t off = 0;
    float* hbuf = ws + off;           off += (size_t)NN * 128;
    float* fA   = ws + off;           off += (size_t)NN * 128;
    float* fB   = ws + off;           off += (size_t)NN * 128;
    float* als  = ws + off;           off += (size_t)NN * 8;
    float* ald  = ws + off;           off += (size_t)NN * 8;
    float* den  = ws + off;           off += (size_t)NN * 8;
    unsigned* maxb = (unsigned*)(ws + off); off += (size_t)NN * 8;
    float* ebuf = ws + off;           off += (size_t)ETOT * 8;

    const int TB = 256;

    // ---------- Layer 0: x -> fA (H=8, C=16) ----------
    hipMemsetAsync(maxb, 0, (size_t)NN * 8 * 4, stream);
    hipMemsetAsync(den,  0, (size_t)NN * 8 * 4, stream);
    hipMemsetAsync(fA,   0, (size_t)NN * 128 * 4, stream);
    gemm_att_kernel<128, 8, 16><<<NN, 128, 0, stream>>>(x, W0, as0, ad0, hbuf, als, ald);
    att_logit_max<8><<<(ETOT + TB - 1) / TB, TB, 0, stream>>>(ei, als, ald, ebuf, maxb);
    att_exp_sum<8><<<(ETOT * 8 + TB - 1) / TB, TB, 0, stream>>>(ei, ebuf, maxb, den);
    aggregate_kernel<8, 16><<<(int)(((size_t)ETOT * 128 + TB - 1) / TB), TB, 0, stream>>>(ei, hbuf, ebuf, fA);
    finalize_kernel<8, 16, true><<<(NN * 128 + TB - 1) / TB, TB, 0, stream>>>(fA, den, b0, fA);

    // ---------- Layer 1: fA -> fB (H=8, C=16) ----------
    hipMemsetAsync(maxb, 0, (size_t)NN * 8 * 4, stream);
    hipMemsetAsync(den,  0, (size_t)NN * 8 * 4, stream);
    hipMemsetAsync(fB,   0, (size_t)NN * 128 * 4, stream);
    gemm_att_kernel<128, 8, 16><<<NN, 128, 0, stream>>>(fA, W1, as1, ad1, hbuf, als, ald);
    att_logit_max<8><<<(ETOT + TB - 1) / TB, TB, 0, stream>>>(ei, als, ald, ebuf, maxb);
    att_exp_sum<8><<<(ETOT * 8 + TB - 1) / TB, TB, 0, stream>>>(ei, ebuf, maxb, den);
    aggregate_kernel<8, 16><<<(int)(((size_t)ETOT * 128 + TB - 1) / TB), TB, 0, stream>>>(ei, hbuf, ebuf, fB);
    finalize_kernel<8, 16, true><<<(NN * 128 + TB - 1) / TB, TB, 0, stream>>>(fB, den, b1, fB);

    // ---------- Layer 2: fB -> out (H=1, C=40) ----------
    hipMemsetAsync(maxb, 0, (size_t)NN * 1 * 4, stream);
    hipMemsetAsync(den,  0, (size_t)NN * 1 * 4, stream);
    hipMemsetAsync(fA,   0, (size_t)NN * 40 * 4, stream);
    gemm_att_kernel<128, 1, 40><<<NN, 128, 0, stream>>>(fB, W2, as2, ad2, hbuf, als, ald);
    att_logit_max<1><<<(ETOT + TB - 1) / TB, TB, 0, stream>>>(ei, als, ald, ebuf, maxb);
    att_exp_sum<1><<<(ETOT * 1 + TB - 1) / TB, TB, 0, stream>>>(ei, ebuf, maxb, den);
    aggregate_kernel<1, 40><<<(int)(((size_t)ETOT * 40 + TB - 1) / TB), TB, 0, stream>>>(ei, hbuf, ebuf, fA);
    finalize_kernel<1, 40, false><<<(NN * 40 + TB - 1) / TB, TB, 0, stream>>>(fA, den, b2, out);
}

// Round 2
// 601.750 us; speedup vs baseline: 3.1880x; 3.1880x over previous
//
#include <hip/hip_runtime.h>

#define NN   50000
#define ERAW 800000
#define ETOT 850000

__device__ __forceinline__ void edge_sd(const int* __restrict__ ei, int e, int& s, int& d) {
    if (e < ERAW) { s = ei[e]; d = ei[ERAW + e]; }
    else { int n = e - ERAW; s = n; d = n; }
}

// ---------------- CSR build (by destination) ----------------
__global__ void k_hist(const int* __restrict__ ei, int* __restrict__ cnt) {
    int e = blockIdx.x * blockDim.x + threadIdx.x;
    if (e >= ETOT) return;
    int s, d; edge_sd(ei, e, s, d); (void)s;
    atomicAdd(&cnt[d], 1);
}

__global__ void k_scan1(const int* __restrict__ cnt, int* __restrict__ excl, int* __restrict__ bsums) {
    __shared__ int tmp[1024];
    int t = threadIdx.x, g = blockIdx.x * 1024 + t;
    int v = (g < NN) ? cnt[g] : 0;
    tmp[t] = v;
    __syncthreads();
    for (int off = 1; off < 1024; off <<= 1) {
        int u = (t >= off) ? tmp[t - off] : 0;
        __syncthreads();
        tmp[t] += u;
        __syncthreads();
    }
    if (g < NN) excl[g] = tmp[t] - v;
    if (t == 1023) bsums[blockIdx.x] = tmp[t];
}

__global__ void k_scan2(int* bsums, int nb) {
    if (threadIdx.x == 0 && blockIdx.x == 0) {
        int acc = 0;
        for (int i = 0; i < nb; ++i) { int v = bsums[i]; bsums[i] = acc; acc += v; }
    }
}

__global__ void k_scan3(const int* __restrict__ excl, const int* __restrict__ bsums,
                        int* __restrict__ row_ptr, int* __restrict__ cursor) {
    int g = blockIdx.x * blockDim.x + threadIdx.x;
    if (g > NN) return;
    int v = (g < NN) ? (excl[g] + bsums[g >> 10]) : ETOT;
    row_ptr[g] = v;
    if (g < NN) cursor[g] = v;
}

__global__ void k_scatter(const int* __restrict__ ei, int* __restrict__ cursor,
                          int* __restrict__ src_sorted, int* __restrict__ dst_sorted) {
    int e = blockIdx.x * blockDim.x + threadIdx.x;
    if (e >= ETOT) return;
    int s, d; edge_sd(ei, e, s, d);
    int pos = atomicAdd(&cursor[d], 1);
    src_sorted[pos] = s;
    dst_sorted[pos] = d;
}

// ---------------- W transpose (so GEMM reads W rows as float4) ----------------
__global__ void k_transpose(const float* __restrict__ W, float* __restrict__ Wt, int K, int NC) {
    int i = blockIdx.x * blockDim.x + threadIdx.x;
    if (i >= K * NC) return;
    int k = i / NC, c = i - k * NC;
    Wt[c * K + k] = W[i];
}

// ---------------- GEMM + attention coefficients ----------------
// 8 nodes per block of 128 threads; x staged in LDS; Wt[col][k] read as float4.
template<int F_IN, int H, int C>
__global__ void gemm_att2(const float* __restrict__ x, const float* __restrict__ Wt,
                          const float* __restrict__ asrc, const float* __restrict__ adst,
                          float* __restrict__ h, float* __restrict__ als, float* __restrict__ ald)
{
    constexpr int HC = H * C;
    constexpr int NPB = 8;
    __shared__ float xs[NPB * F_IN];
    int t = threadIdx.x;            // 128
    int n0 = blockIdx.x * NPB;
    for (int idx = t; idx < NPB * F_IN; idx += 128) {
        int n = idx / F_IN, k = idx - n * F_IN;
        int nn = n0 + n;
        xs[idx] = (nn < NN) ? x[(size_t)nn * F_IN + k] : 0.f;
    }
    __syncthreads();
    float acc[NPB];
    #pragma unroll
    for (int n = 0; n < NPB; ++n) acc[n] = 0.f;
    if (t < HC) {
        const float4* wt4 = (const float4*)(Wt + t * F_IN);
        const float4* xs4 = (const float4*)xs;
        for (int kc = 0; kc < F_IN / 4; ++kc) {
            float4 w = wt4[kc];
            #pragma unroll
            for (int n = 0; n < NPB; ++n) {
                float4 xv = xs4[n * (F_IN / 4) + kc];
                acc[n] = fmaf(w.x, xv.x, acc[n]);
                acc[n] = fmaf(w.y, xv.y, acc[n]);
                acc[n] = fmaf(w.z, xv.z, acc[n]);
                acc[n] = fmaf(w.w, xv.w, acc[n]);
            }
        }
    }
    float av_s = (t < HC) ? asrc[t] : 0.f;
    float av_d = (t < HC) ? adst[t] : 0.f;
    #pragma unroll
    for (int n = 0; n < NPB; ++n) {
        int nn = n0 + n;
        if (nn < NN) {
            if (t < HC) h[(size_t)nn * HC + t] = acc[n];
            float v1 = acc[n] * av_s;
            float v2 = acc[n] * av_d;
            if (HC == 128) {
                #pragma unroll
                for (int mask = 1; mask < 16; mask <<= 1) {
                    v1 += __shfl_xor(v1, mask);
                    v2 += __shfl_xor(v2, mask);
                }
                if ((t & 15) == 0) { als[nn * H + t / C] = v1; ald[nn * H + t / C] = v2; }
            } else {
                #pragma unroll
                for (int mask = 1; mask < 64; mask <<= 1) {
                    v1 += __shfl_xor(v1, mask);
                    v2 += __shfl_xor(v2, mask);
                }
                if (t == 0) { als[nn] = v1; ald[nn] = v2; }
            }
        }
    }
}

// ---------------- edge logits (sorted edge order, no atomics) ----------------
__global__ void edge_logit8(const int* __restrict__ src_sorted, const int* __restrict__ dst_sorted,
                            const float* __restrict__ als, const float* __restrict__ ald,
                            float* __restrict__ ebuf)
{
    int e = blockIdx.x * blockDim.x + threadIdx.x;
    if (e >= ETOT) return;
    int s = src_sorted[e], d = dst_sorted[e];
    const float4* als4 = (const float4*)als;
    const float4* ald4 = (const float4*)ald;
    float4* eb4 = (float4*)ebuf;
    #pragma unroll
    for (int q = 0; q < 2; ++q) {
        float4 a = als4[s * 2 + q];
        float4 b = ald4[d * 2 + q];
        float4 r;
        r.x = a.x + b.x; r.x = r.x > 0.f ? r.x : 0.2f * r.x;
        r.y = a.y + b.y; r.y = r.y > 0.f ? r.y : 0.2f * r.y;
        r.z = a.z + b.z; r.z = r.z > 0.f ? r.z : 0.2f * r.z;
        r.w = a.w + b.w; r.w = r.w > 0.f ? r.w : 0.2f * r.w;
        eb4[(size_t)e * 2 + q] = r;
    }
}

__global__ void edge_logit1(const int* __restrict__ src_sorted, const int* __restrict__ dst_sorted,
                            const float* __restrict__ als, const float* __restrict__ ald,
                            float* __restrict__ ebuf)
{
    int e = blockIdx.x * blockDim.x + threadIdx.x;
    if (e >= ETOT) return;
    float v = als[src_sorted[e]] + ald[dst_sorted[e]];
    ebuf[e] = v > 0.f ? v : 0.2f * v;
}

// ---------------- per-destination fused softmax + aggregate + finalize ----------------
// one wave per dst node; H=8, C=16 (HC=128): lane j covers features 2j,2j+1 (head j>>3)
template<bool RELU>
__global__ void dst_agg128(const int* __restrict__ row_ptr, const int* __restrict__ src_sorted,
                           const float* __restrict__ ebuf, const float* __restrict__ hbuf,
                           const float* __restrict__ bias, float* __restrict__ out)
{
    int w = (blockIdx.x * blockDim.x + threadIdx.x) >> 6;
    if (w >= NN) return;
    int j = threadIdx.x & 63;
    int start = row_ptr[w], end = row_ptr[w + 1];
    int hh = j & 7, slot = j >> 3;
    // phase A: per-head max (lane j handles head j&7, edge-slot j>>3)
    float m = -1e30f;
    for (int i = start + slot; i < end; i += 8) m = fmaxf(m, ebuf[(size_t)i * 8 + hh]);
    m = fmaxf(m, __shfl_xor(m, 8));
    m = fmaxf(m, __shfl_xor(m, 16));
    m = fmaxf(m, __shfl_xor(m, 32));
    // phase B: per-head denominator
    float sden = 0.f;
    for (int i = start + slot; i < end; i += 8) sden += __expf(ebuf[(size_t)i * 8 + hh] - m);
    sden += __shfl_xor(sden, 8);
    sden += __shfl_xor(sden, 16);
    sden += __shfl_xor(sden, 32);
    // redistribute: lane j needs head j>>3 (held by lane j>>3)
    int myh = j >> 3;
    float mf = __shfl(m, myh);
    float sf = __shfl(sden, myh);
    float inv = 1.f / (sf + 1e-16f);
    // phase C: gather-accumulate numerator
    const float2* h2 = (const float2*)hbuf;
    float2 acc = make_float2(0.f, 0.f);
    for (int i = start; i < end; ++i) {
        int sidx = src_sorted[i];
        float al = __expf(ebuf[(size_t)i * 8 + myh] - mf);
        float2 hv = h2[(size_t)sidx * 64 + j];
        acc.x = fmaf(hv.x, al, acc.x);
        acc.y = fmaf(hv.y, al, acc.y);
    }
    float2 o;
    o.x = acc.x * inv + bias[2 * j];
    o.y = acc.y * inv + bias[2 * j + 1];
    if (RELU) { o.x = fmaxf(o.x, 0.f); o.y = fmaxf(o.y, 0.f); }
    ((float2*)out)[(size_t)w * 64 + j] = o;
}

// H=1, C=40
__global__ void dst_agg40(const int* __restrict__ row_ptr, const int* __restrict__ src_sorted,
                          const float* __restrict__ ebuf, const float* __restrict__ hbuf,
                          const float* __restrict__ bias, float* __restrict__ out)
{
    int w = (blockIdx.x * blockDim.x + threadIdx.x) >> 6;
    if (w >= NN) return;
    int j = threadIdx.x & 63;
    int start = row_ptr[w], end = row_ptr[w + 1];
    float m = -1e30f;
    for (int i = start + j; i < end; i += 64) m = fmaxf(m, ebuf[i]);
    #pragma unroll
    for (int mask = 1; mask < 64; mask <<= 1) m = fmaxf(m, __shfl_xor(m, mask));
    float sden = 0.f;
    for (int i = start + j; i < end; i += 64) sden += __expf(ebuf[i] - m);
    #pragma unroll
    for (int mask = 1; mask < 64; mask <<= 1) sden += __shfl_xor(sden, mask);
    float inv = 1.f / (sden + 1e-16f);
    float acc = 0.f;
    for (int i = start; i < end; ++i) {
        float al = __expf(ebuf[i] - m);
        int sidx = src_sorted[i];
        if (j < 40) acc = fmaf(hbuf[(size_t)sidx * 40 + j], al, acc);
    }
    if (j < 40) out[(size_t)w * 40 + j] = acc * inv + bias[j];
}

extern "C" void kernel_launch(void* const* d_in, const int* in_sizes, int n_in,
                              void* d_out, int out_size, void* d_ws, size_t ws_size,
                              hipStream_t stream) {
    const float* x   = (const float*)d_in[0];
    const int*   ei  = (const int*)d_in[1];
    const float* W0  = (const float*)d_in[2];
    const float* as0 = (const float*)d_in[3];
    const float* ad0 = (const float*)d_in[4];
    const float* b0  = (const float*)d_in[5];
    const float* W1  = (const float*)d_in[6];
    const float* as1 = (const float*)d_in[7];
    const float* ad1 = (const float*)d_in[8];
    const float* b1  = (const float*)d_in[9];
    const float* W2  = (const float*)d_in[10];
    const float* as2 = (const float*)d_in[11];
    const float* ad2 = (const float*)d_in[12];
    const float* b2  = (const float*)d_in[13];
    float* out = (float*)d_out;

    float* ws = (float*)d_ws;
    size_t off = 0;
    float* hbuf = ws + off; off += (size_t)NN * 128;
    float* fA   = ws + off; off += (size_t)NN * 128;
    float* fB   = ws + off; off += (size_t)NN * 128;
    float* als  = ws + off; off += (size_t)NN * 8;
    float* ald  = ws + off; off += (size_t)NN * 8;
    float* ebuf = ws + off; off += (size_t)ETOT * 8;
    float* Wt   = ws + off; off += 128 * 128;
    int* ibase      = (int*)(ws + off);
    int* cnt        = ibase;                 ibase += NN;
    int* excl       = ibase;                 ibase += NN;
    int* bsums      = ibase;                 ibase += 64;
    int* row_ptr    = ibase;                 ibase += NN + 1;
    int* cursor     = ibase;                 ibase += NN + 1;   // keep alignment
    int* src_sorted = ibase;                 ibase += ETOT;
    int* dst_sorted = ibase;                 ibase += ETOT;

    const int TB = 256;
    const int EG = (ETOT + TB - 1) / TB;
    const int NSCAN = (NN + 1023) / 1024;

    // ---- CSR build (once; shared by all 3 layers) ----
    hipMemsetAsync(cnt, 0, (size_t)NN * sizeof(int), stream);
    k_hist<<<EG, TB, 0, stream>>>(ei, cnt);
    k_scan1<<<NSCAN, 1024, 0, stream>>>(cnt, excl, bsums);
    k_scan2<<<1, 64, 0, stream>>>(bsums, NSCAN);
    k_scan3<<<(NN + 1 + TB - 1) / TB, TB, 0, stream>>>(excl, bsums, row_ptr, cursor);
    k_scatter<<<EG, TB, 0, stream>>>(ei, cursor, src_sorted, dst_sorted);

    const int GGEMM = (NN + 7) / 8;
    const int GAGG = (NN * 64 + TB - 1) / TB;

    // ---- Layer 0 ----
    k_transpose<<<(128 * 128 + TB - 1) / TB, TB, 0, stream>>>(W0, Wt, 128, 128);
    gemm_att2<128, 8, 16><<<GGEMM, 128, 0, stream>>>(x, Wt, as0, ad0, hbuf, als, ald);
    edge_logit8<<<EG, TB, 0, stream>>>(src_sorted, dst_sorted, als, ald, ebuf);
    dst_agg128<true><<<GAGG, TB, 0, stream>>>(row_ptr, src_sorted, ebuf, hbuf, b0, fA);

    // ---- Layer 1 ----
    k_transpose<<<(128 * 128 + TB - 1) / TB, TB, 0, stream>>>(W1, Wt, 128, 128);
    gemm_att2<128, 8, 16><<<GGEMM, 128, 0, stream>>>(fA, Wt, as1, ad1, hbuf, als, ald);
    edge_logit8<<<EG, TB, 0, stream>>>(src_sorted, dst_sorted, als, ald, ebuf);
    dst_agg128<true><<<GAGG, TB, 0, stream>>>(row_ptr, src_sorted, ebuf, hbuf, b1, fB);

    // ---- Layer 2 ----
    k_transpose<<<(128 * 40 + TB - 1) / TB, TB, 0, stream>>>(W2, Wt, 128, 40);
    gemm_att2<128, 1, 40><<<GGEMM, 128, 0, stream>>>(fB, Wt, as2, ad2, hbuf, als, ald);
    edge_logit1<<<EG, TB, 0, stream>>>(src_sorted, dst_sorted, als, ald, ebuf);
    dst_agg40<<<GAGG, TB, 0, stream>>>(row_ptr, src_sorted, ebuf, hbuf, b2, out);
}

// Round 3
// 511.736 us; speedup vs baseline: 3.7487x; 1.1759x over previous
//
#include <hip/hip_runtime.h>

#define NN   50000
#define ERAW 800000
#define ETOT 850000

__device__ __forceinline__ void edge_sd(const int* __restrict__ ei, int e, int& s, int& d) {
    if (e < ERAW) { s = ei[e]; d = ei[ERAW + e]; }
    else { int n = e - ERAW; s = n; d = n; }
}

// ---------------- CSR build (by destination) ----------------
__global__ void k_hist(const int* __restrict__ ei, int* __restrict__ cnt) {
    int e = blockIdx.x * blockDim.x + threadIdx.x;
    if (e >= ETOT) return;
    int s, d; edge_sd(ei, e, s, d); (void)s;
    atomicAdd(&cnt[d], 1);
}

__global__ void k_scan1(const int* __restrict__ cnt, int* __restrict__ excl, int* __restrict__ bsums) {
    __shared__ int tmp[1024];
    int t = threadIdx.x, g = blockIdx.x * 1024 + t;
    int v = (g < NN) ? cnt[g] : 0;
    tmp[t] = v;
    __syncthreads();
    for (int off = 1; off < 1024; off <<= 1) {
        int u = (t >= off) ? tmp[t - off] : 0;
        __syncthreads();
        tmp[t] += u;
        __syncthreads();
    }
    if (g < NN) excl[g] = tmp[t] - v;
    if (t == 1023) bsums[blockIdx.x] = tmp[t];
}

__global__ void k_scan2(int* bsums, int nb) {
    if (threadIdx.x == 0 && blockIdx.x == 0) {
        int acc = 0;
        for (int i = 0; i < nb; ++i) { int v = bsums[i]; bsums[i] = acc; acc += v; }
    }
}

__global__ void k_scan3(const int* __restrict__ excl, const int* __restrict__ bsums,
                        int* __restrict__ row_ptr, int* __restrict__ cursor) {
    int g = blockIdx.x * blockDim.x + threadIdx.x;
    if (g > NN) return;
    int v = (g < NN) ? (excl[g] + bsums[g >> 10]) : ETOT;
    row_ptr[g] = v;
    if (g < NN) cursor[g] = v;
}

__global__ void k_scatter(const int* __restrict__ ei, int* __restrict__ cursor,
                          int* __restrict__ src_sorted) {
    int e = blockIdx.x * blockDim.x + threadIdx.x;
    if (e >= ETOT) return;
    int s, d; edge_sd(ei, e, s, d);
    int pos = atomicAdd(&cursor[d], 1);
    src_sorted[pos] = s;
}

// ---------------- W transposes (one kernel for all three layers) ----------------
__global__ void k_transpose3(const float* __restrict__ W0, const float* __restrict__ W1,
                             const float* __restrict__ W2, float* __restrict__ Wt0,
                             float* __restrict__ Wt1, float* __restrict__ Wt2) {
    int i = blockIdx.x * blockDim.x + threadIdx.x;
    if (i < 128 * 128) {
        int k = i >> 7, c = i & 127;
        Wt0[c * 128 + k] = W0[i];
        Wt1[c * 128 + k] = W1[i];
    }
    if (i < 128 * 40) {
        int k = i / 40, c = i - k * 40;
        Wt2[c * 128 + k] = W2[i];
    }
}

// ---------------- GEMM + attention coefficients ----------------
// NPB nodes/block; x rows read via wave-uniform float4 (scalar-load path),
// W column per thread via float4 from L2. NN must be divisible by NPB (50000/16=3125).
template<int H, int C, int NPB, int TPB>
__global__ void gemm_att3(const float* __restrict__ x, const float* __restrict__ Wt,
                          const float* __restrict__ asrc, const float* __restrict__ adst,
                          float* __restrict__ h, float* __restrict__ als, float* __restrict__ ald)
{
    constexpr int F_IN = 128;
    constexpr int HC = H * C;
    int t = threadIdx.x;
    int n0 = blockIdx.x * NPB;
    int tc = (t < HC) ? t : HC - 1;
    const float4* wt4 = (const float4*)(Wt + (size_t)tc * F_IN);
    float acc[NPB];
    #pragma unroll
    for (int n = 0; n < NPB; ++n) acc[n] = 0.f;
    for (int kc = 0; kc < F_IN / 4; ++kc) {
        float4 w = wt4[kc];
        #pragma unroll
        for (int n = 0; n < NPB; ++n) {
            float4 xv = ((const float4*)(x + (size_t)(n0 + n) * F_IN))[kc];  // wave-uniform
            acc[n] = fmaf(w.x, xv.x, acc[n]);
            acc[n] = fmaf(w.y, xv.y, acc[n]);
            acc[n] = fmaf(w.z, xv.z, acc[n]);
            acc[n] = fmaf(w.w, xv.w, acc[n]);
        }
    }
    float av_s = (t < HC) ? asrc[t] : 0.f;
    float av_d = (t < HC) ? adst[t] : 0.f;
    #pragma unroll
    for (int n = 0; n < NPB; ++n) {
        int nn = n0 + n;
        if (t < HC) h[(size_t)nn * HC + t] = acc[n];
        float v1 = acc[n] * av_s;
        float v2 = acc[n] * av_d;
        if (HC == 128) {
            #pragma unroll
            for (int mask = 1; mask < 16; mask <<= 1) {
                v1 += __shfl_xor(v1, mask);
                v2 += __shfl_xor(v2, mask);
            }
            if ((t & 15) == 0) { als[nn * H + (t >> 4)] = v1; ald[nn * H + (t >> 4)] = v2; }
        } else {
            #pragma unroll
            for (int mask = 1; mask < 64; mask <<= 1) {
                v1 += __shfl_xor(v1, mask);
                v2 += __shfl_xor(v2, mask);
            }
            if (t == 0) { als[nn] = v1; ald[nn] = v2; }
        }
    }
}

// ---------------- fused single-pass softmax + aggregate + finalize ----------------
// One wave per dst node. No max-subtraction (logits |e| << 80, f32 exp safe; alpha identical).
// H=8,C=16: lane j owns features 2j,2j+1 (head j>>3). Denominator: every lane sums over
// ALL edges, so per-lane sum is already the full per-head denominator.
template<bool RELU>
__global__ void dst_agg128(const int* __restrict__ row_ptr, const int* __restrict__ src_sorted,
                           const float* __restrict__ als, const float* __restrict__ ald,
                           const float* __restrict__ hbuf, const float* __restrict__ bias,
                           float* __restrict__ out)
{
    int w = (blockIdx.x * blockDim.x + threadIdx.x) >> 6;
    if (w >= NN) return;
    int j = threadIdx.x & 63;
    int myh = j >> 3;
    float aldv = ald[w * 8 + myh];
    int start = row_ptr[w], end = row_ptr[w + 1];
    const float2* h2 = (const float2*)hbuf;
    float2 acc = make_float2(0.f, 0.f);
    float den = 0.f;
    int i = start;
    for (; i + 2 <= end; i += 2) {
        int s0 = src_sorted[i], s1 = src_sorted[i + 1];
        float e0 = als[s0 * 8 + myh] + aldv;
        float e1 = als[s1 * 8 + myh] + aldv;
        float2 hv0 = h2[(size_t)s0 * 64 + j];
        float2 hv1 = h2[(size_t)s1 * 64 + j];
        e0 = e0 > 0.f ? e0 : 0.2f * e0;
        e1 = e1 > 0.f ? e1 : 0.2f * e1;
        float a0 = __expf(e0);
        float a1 = __expf(e1);
        den += a0 + a1;
        acc.x = fmaf(hv0.x, a0, acc.x);
        acc.y = fmaf(hv0.y, a0, acc.y);
        acc.x = fmaf(hv1.x, a1, acc.x);
        acc.y = fmaf(hv1.y, a1, acc.y);
    }
    for (; i < end; ++i) {
        int s0 = src_sorted[i];
        float e0 = als[s0 * 8 + myh] + aldv;
        e0 = e0 > 0.f ? e0 : 0.2f * e0;
        float a0 = __expf(e0);
        den += a0;
        float2 hv0 = h2[(size_t)s0 * 64 + j];
        acc.x = fmaf(hv0.x, a0, acc.x);
        acc.y = fmaf(hv0.y, a0, acc.y);
    }
    float inv = 1.f / (den + 1e-16f);
    float2 o;
    o.x = acc.x * inv + bias[2 * j];
    o.y = acc.y * inv + bias[2 * j + 1];
    if (RELU) { o.x = fmaxf(o.x, 0.f); o.y = fmaxf(o.y, 0.f); }
    ((float2*)out)[(size_t)w * 64 + j] = o;
}

// H=1, C=40: lanes 0..39 own features; all lanes compute the denominator.
__global__ void dst_agg40(const int* __restrict__ row_ptr, const int* __restrict__ src_sorted,
                          const float* __restrict__ als, const float* __restrict__ ald,
                          const float* __restrict__ hbuf, const float* __restrict__ bias,
                          float* __restrict__ out)
{
    int w = (blockIdx.x * blockDim.x + threadIdx.x) >> 6;
    if (w >= NN) return;
    int j = threadIdx.x & 63;
    float aldv = ald[w];
    int start = row_ptr[w], end = row_ptr[w + 1];
    float acc = 0.f, den = 0.f;
    int i = start;
    for (; i + 2 <= end; i += 2) {
        int s0 = src_sorted[i], s1 = src_sorted[i + 1];
        float e0 = als[s0] + aldv;
        float e1 = als[s1] + aldv;
        float hv0 = (j < 40) ? hbuf[(size_t)s0 * 40 + j] : 0.f;
        float hv1 = (j < 40) ? hbuf[(size_t)s1 * 40 + j] : 0.f;
        e0 = e0 > 0.f ? e0 : 0.2f * e0;
        e1 = e1 > 0.f ? e1 : 0.2f * e1;
        float a0 = __expf(e0);
        float a1 = __expf(e1);
        den += a0 + a1;
        acc = fmaf(hv0, a0, acc);
        acc = fmaf(hv1, a1, acc);
    }
    for (; i < end; ++i) {
        int s0 = src_sorted[i];
        float e0 = als[s0] + aldv;
        e0 = e0 > 0.f ? e0 : 0.2f * e0;
        float a0 = __expf(e0);
        den += a0;
        if (j < 40) acc = fmaf(hbuf[(size_t)s0 * 40 + j], a0, acc);
    }
    if (j < 40) out[(size_t)w * 40 + j] = acc / (den + 1e-16f) + bias[j];
}

extern "C" void kernel_launch(void* const* d_in, const int* in_sizes, int n_in,
                              void* d_out, int out_size, void* d_ws, size_t ws_size,
                              hipStream_t stream) {
    const float* x   = (const float*)d_in[0];
    const int*   ei  = (const int*)d_in[1];
    const float* W0  = (const float*)d_in[2];
    const float* as0 = (const float*)d_in[3];
    const float* ad0 = (const float*)d_in[4];
    const float* b0  = (const float*)d_in[5];
    const float* W1  = (const float*)d_in[6];
    const float* as1 = (const float*)d_in[7];
    const float* ad1 = (const float*)d_in[8];
    const float* b1  = (const float*)d_in[9];
    const float* W2  = (const float*)d_in[10];
    const float* as2 = (const float*)d_in[11];
    const float* ad2 = (const float*)d_in[12];
    const float* b2  = (const float*)d_in[13];
    float* out = (float*)d_out;

    float* ws = (float*)d_ws;
    size_t off = 0;
    float* hbuf = ws + off; off += (size_t)NN * 128;
    float* fA   = ws + off; off += (size_t)NN * 128;
    float* fB   = ws + off; off += (size_t)NN * 128;
    float* als  = ws + off; off += (size_t)NN * 8;
    float* ald  = ws + off; off += (size_t)NN * 8;
    float* Wt0  = ws + off; off += 128 * 128;
    float* Wt1  = ws + off; off += 128 * 128;
    float* Wt2  = ws + off; off += 128 * 40;
    int* ibase      = (int*)(ws + off);
    int* cnt        = ibase; ibase += NN;
    int* excl       = ibase; ibase += NN;
    int* bsums      = ibase; ibase += 64;
    int* row_ptr    = ibase; ibase += NN + 1;
    int* cursor     = ibase; ibase += NN + 1;
    int* src_sorted = ibase; ibase += ETOT;

    const int TB = 256;
    const int EG = (ETOT + TB - 1) / TB;
    const int NSCAN = (NN + 1023) / 1024;

    // ---- CSR build (once; shared by all 3 layers) ----
    hipMemsetAsync(cnt, 0, (size_t)NN * sizeof(int), stream);
    k_hist<<<EG, TB, 0, stream>>>(ei, cnt);
    k_scan1<<<NSCAN, 1024, 0, stream>>>(cnt, excl, bsums);
    k_scan2<<<1, 64, 0, stream>>>(bsums, NSCAN);
    k_scan3<<<(NN + 1 + TB - 1) / TB, TB, 0, stream>>>(excl, bsums, row_ptr, cursor);
    k_scatter<<<EG, TB, 0, stream>>>(ei, cursor, src_sorted);
    k_transpose3<<<(128 * 128 + TB - 1) / TB, TB, 0, stream>>>(W0, W1, W2, Wt0, Wt1, Wt2);

    const int GGEMM = NN / 16;                       // 3125 (exact)
    const int GAGG  = (NN * 64 + TB - 1) / TB;       // one wave per node

    // ---- Layer 0 ----
    gemm_att3<8, 16, 16, 128><<<GGEMM, 128, 0, stream>>>(x, Wt0, as0, ad0, hbuf, als, ald);
    dst_agg128<true><<<GAGG, TB, 0, stream>>>(row_ptr, src_sorted, als, ald, hbuf, b0, fA);

    // ---- Layer 1 ----
    gemm_att3<8, 16, 16, 128><<<GGEMM, 128, 0, stream>>>(fA, Wt1, as1, ad1, hbuf, als, ald);
    dst_agg128<true><<<GAGG, TB, 0, stream>>>(row_ptr, src_sorted, als, ald, hbuf, b1, fB);

    // ---- Layer 2 ----
    gemm_att3<1, 40, 16, 64><<<GGEMM, 64, 0, stream>>>(fB, Wt2, as2, ad2, hbuf, als, ald);
    dst_agg40<<<GAGG, TB, 0, stream>>>(row_ptr, src_sorted, als, ald, hbuf, b2, out);
}

// Round 4
// 378.269 us; speedup vs baseline: 5.0714x; 1.3528x over previous
//
#include <hip/hip_runtime.h>

#define NN   50000
#define ERAW 800000
#define ETOT 850000

__device__ __forceinline__ void edge_sd(const int* __restrict__ ei, int e, int& s, int& d) {
    if (e < ERAW) { s = ei[e]; d = ei[ERAW + e]; }
    else { int n = e - ERAW; s = n; d = n; }
}

// ---------------- CSR build (by destination) ----------------
__global__ void k_hist(const int* __restrict__ ei, int* __restrict__ cnt) {
    int e = blockIdx.x * blockDim.x + threadIdx.x;
    if (e >= ETOT) return;
    int s, d; edge_sd(ei, e, s, d); (void)s;
    atomicAdd(&cnt[d], 1);
}

__global__ void k_scan1(const int* __restrict__ cnt, int* __restrict__ excl, int* __restrict__ bsums) {
    __shared__ int tmp[1024];
    int t = threadIdx.x, g = blockIdx.x * 1024 + t;
    int v = (g < NN) ? cnt[g] : 0;
    tmp[t] = v;
    __syncthreads();
    for (int off = 1; off < 1024; off <<= 1) {
        int u = (t >= off) ? tmp[t - off] : 0;
        __syncthreads();
        tmp[t] += u;
        __syncthreads();
    }
    if (g < NN) excl[g] = tmp[t] - v;
    if (t == 1023) bsums[blockIdx.x] = tmp[t];
}

__global__ void k_scan2(int* bsums, int nb) {
    if (threadIdx.x == 0 && blockIdx.x == 0) {
        int acc = 0;
        for (int i = 0; i < nb; ++i) { int v = bsums[i]; bsums[i] = acc; acc += v; }
    }
}

__global__ void k_scan3(const int* __restrict__ excl, const int* __restrict__ bsums,
                        int* __restrict__ row_ptr, int* __restrict__ cursor) {
    int g = blockIdx.x * blockDim.x + threadIdx.x;
    if (g > NN) return;
    int v = (g < NN) ? (excl[g] + bsums[g >> 10]) : ETOT;
    row_ptr[g] = v;
    if (g < NN) cursor[g] = v;
}

__global__ void k_scatter(const int* __restrict__ ei, int* __restrict__ cursor,
                          int* __restrict__ src_sorted) {
    int e = blockIdx.x * blockDim.x + threadIdx.x;
    if (e >= ETOT) return;
    int s, d; edge_sd(ei, e, s, d);
    int pos = atomicAdd(&cursor[d], 1);
    src_sorted[pos] = s;
}

// ---------------- GEMM + attention coefficients (layers 0/1: 128 -> 8x16) ----------------
// 256 threads; 32 nodes x 128 cols per block; each thread 4 nodes x 4 cols.
// K tiled in 4 chunks of 32: W-tile [32k][128c] (16KB) + x-tile [32n][32k] (4KB) in LDS.
#define FMA4(xc, wv, i) \
    acc[i][0] = fmaf(xc, wv.x, acc[i][0]); \
    acc[i][1] = fmaf(xc, wv.y, acc[i][1]); \
    acc[i][2] = fmaf(xc, wv.z, acc[i][2]); \
    acc[i][3] = fmaf(xc, wv.w, acc[i][3]);

__global__ __launch_bounds__(256) void gemm_att128(
    const float* __restrict__ x, const float* __restrict__ W,
    const float* __restrict__ asrc, const float* __restrict__ adst,
    float* __restrict__ h, float* __restrict__ als, float* __restrict__ ald)
{
    __shared__ float ws[32 * 128];
    __shared__ float xs[32 * 32];
    int t = threadIdx.x;
    int tx = t & 31, ty = t >> 5;      // cols 4tx..4tx+3, nodes 4ty..4ty+3
    int n0 = blockIdx.x * 32;

    float acc[4][4];
    #pragma unroll
    for (int i = 0; i < 4; ++i)
        #pragma unroll
        for (int j = 0; j < 4; ++j) acc[i][j] = 0.f;

    int ngx = n0 + (t >> 3); if (ngx >= NN) ngx = NN - 1;
    const float4* xrow = (const float4*)(x + (size_t)ngx * 128);
    int kcx = t & 7;

    for (int kt = 0; kt < 4; ++kt) {
        const float4* Wg = (const float4*)(W + (size_t)kt * 32 * 128);
        float4* ws4 = (float4*)ws;
        #pragma unroll
        for (int i = 0; i < 4; ++i) ws4[i * 256 + t] = Wg[i * 256 + t];
        ((float4*)xs)[t] = xrow[kt * 8 + kcx];
        __syncthreads();
        #pragma unroll
        for (int kc = 0; kc < 8; ++kc) {
            float4 wv0 = ((const float4*)(ws + (kc * 4 + 0) * 128))[tx];
            float4 wv1 = ((const float4*)(ws + (kc * 4 + 1) * 128))[tx];
            float4 wv2 = ((const float4*)(ws + (kc * 4 + 2) * 128))[tx];
            float4 wv3 = ((const float4*)(ws + (kc * 4 + 3) * 128))[tx];
            #pragma unroll
            for (int i = 0; i < 4; ++i) {
                float4 xv = ((const float4*)(xs + (4 * ty + i) * 32))[kc];
                FMA4(xv.x, wv0, i)
                FMA4(xv.y, wv1, i)
                FMA4(xv.z, wv2, i)
                FMA4(xv.w, wv3, i)
            }
        }
        __syncthreads();
    }

    float4 as4 = ((const float4*)asrc)[tx];
    float4 ad4 = ((const float4*)adst)[tx];
    int hd = tx >> 2;                    // head of cols 4tx..4tx+3 (C=16)
    #pragma unroll
    for (int i = 0; i < 4; ++i) {
        int n = n0 + 4 * ty + i;
        if (n < NN) {
            float4 hv = make_float4(acc[i][0], acc[i][1], acc[i][2], acc[i][3]);
            ((float4*)(h + (size_t)n * 128))[tx] = hv;
            float v1 = acc[i][0] * as4.x + acc[i][1] * as4.y + acc[i][2] * as4.z + acc[i][3] * as4.w;
            float v2 = acc[i][0] * ad4.x + acc[i][1] * ad4.y + acc[i][2] * ad4.z + acc[i][3] * ad4.w;
            v1 += __shfl_xor(v1, 1); v1 += __shfl_xor(v1, 2);
            v2 += __shfl_xor(v2, 1); v2 += __shfl_xor(v2, 2);
            if ((tx & 3) == 0) { als[n * 8 + hd] = v1; ald[n * 8 + hd] = v2; }
        }
    }
}

// ---------------- GEMM + attention (layer 2: 128 -> 1x40) ----------------
// 256 threads; 16 nodes/block (4 per wave); lane = col (c<40 active).
// W staged [128k][40c] k-major in LDS (20KB), x-tile 16x128 (8KB).
__global__ __launch_bounds__(256) void gemm_att40(
    const float* __restrict__ x, const float* __restrict__ W,
    const float* __restrict__ asrc, const float* __restrict__ adst,
    float* __restrict__ h, float* __restrict__ als, float* __restrict__ ald)
{
    __shared__ float ws[128 * 40];
    __shared__ float xs[16 * 128];
    int t = threadIdx.x;
    int n0 = blockIdx.x * 16;
    #pragma unroll
    for (int i = 0; i < 5; ++i) ((float4*)ws)[i * 256 + t] = ((const float4*)W)[i * 256 + t];
    #pragma unroll
    for (int q = 0; q < 2; ++q) {
        int idx = q * 256 + t;
        int n = idx >> 5, kc = idx & 31;
        ((float4*)xs)[idx] = ((const float4*)(x + (size_t)(n0 + n) * 128))[kc];
    }
    __syncthreads();
    int w = t >> 6, c = t & 63;
    int cc = c < 40 ? c : 39;
    float acc[4] = {0.f, 0.f, 0.f, 0.f};
    #pragma unroll 4
    for (int kc = 0; kc < 32; ++kc) {
        float w0 = ws[(kc * 4 + 0) * 40 + cc];
        float w1 = ws[(kc * 4 + 1) * 40 + cc];
        float w2 = ws[(kc * 4 + 2) * 40 + cc];
        float w3 = ws[(kc * 4 + 3) * 40 + cc];
        #pragma unroll
        for (int i = 0; i < 4; ++i) {
            float4 xv = ((const float4*)(xs + (4 * w + i) * 128))[kc];
            acc[i] = fmaf(xv.x, w0, acc[i]);
            acc[i] = fmaf(xv.y, w1, acc[i]);
            acc[i] = fmaf(xv.z, w2, acc[i]);
            acc[i] = fmaf(xv.w, w3, acc[i]);
        }
    }
    float a_s = (c < 40) ? asrc[c] : 0.f;
    float a_d = (c < 40) ? adst[c] : 0.f;
    #pragma unroll
    for (int i = 0; i < 4; ++i) {
        int n = n0 + 4 * w + i;
        if (c < 40) h[(size_t)n * 40 + c] = acc[i];
        float v1 = acc[i] * a_s, v2 = acc[i] * a_d;
        #pragma unroll
        for (int m = 1; m < 64; m <<= 1) { v1 += __shfl_xor(v1, m); v2 += __shfl_xor(v2, m); }
        if (c == 0) { als[n] = v1; ald[n] = v2; }
    }
}

// ---------------- fused single-pass softmax + aggregate + finalize ----------------
template<bool RELU>
__global__ void dst_agg128(const int* __restrict__ row_ptr, const int* __restrict__ src_sorted,
                           const float* __restrict__ als, const float* __restrict__ ald,
                           const float* __restrict__ hbuf, const float* __restrict__ bias,
                           float* __restrict__ out)
{
    int w = (blockIdx.x * blockDim.x + threadIdx.x) >> 6;
    if (w >= NN) return;
    int j = threadIdx.x & 63;
    int myh = j >> 3;
    float aldv = ald[w * 8 + myh];
    int start = row_ptr[w], end = row_ptr[w + 1];
    const float2* h2 = (const float2*)hbuf;
    float2 acc = make_float2(0.f, 0.f);
    float den = 0.f;
    int i = start;
    for (; i + 4 <= end; i += 4) {
        int s0 = src_sorted[i], s1 = src_sorted[i + 1], s2 = src_sorted[i + 2], s3 = src_sorted[i + 3];
        float e0 = als[s0 * 8 + myh] + aldv;
        float e1 = als[s1 * 8 + myh] + aldv;
        float e2 = als[s2 * 8 + myh] + aldv;
        float e3 = als[s3 * 8 + myh] + aldv;
        float2 hv0 = h2[(size_t)s0 * 64 + j];
        float2 hv1 = h2[(size_t)s1 * 64 + j];
        float2 hv2 = h2[(size_t)s2 * 64 + j];
        float2 hv3 = h2[(size_t)s3 * 64 + j];
        e0 = e0 > 0.f ? e0 : 0.2f * e0;
        e1 = e1 > 0.f ? e1 : 0.2f * e1;
        e2 = e2 > 0.f ? e2 : 0.2f * e2;
        e3 = e3 > 0.f ? e3 : 0.2f * e3;
        float a0 = __expf(e0), a1 = __expf(e1), a2 = __expf(e2), a3 = __expf(e3);
        den += (a0 + a1) + (a2 + a3);
        acc.x = fmaf(hv0.x, a0, acc.x); acc.y = fmaf(hv0.y, a0, acc.y);
        acc.x = fmaf(hv1.x, a1, acc.x); acc.y = fmaf(hv1.y, a1, acc.y);
        acc.x = fmaf(hv2.x, a2, acc.x); acc.y = fmaf(hv2.y, a2, acc.y);
        acc.x = fmaf(hv3.x, a3, acc.x); acc.y = fmaf(hv3.y, a3, acc.y);
    }
    for (; i < end; ++i) {
        int s0 = src_sorted[i];
        float e0 = als[s0 * 8 + myh] + aldv;
        e0 = e0 > 0.f ? e0 : 0.2f * e0;
        float a0 = __expf(e0);
        den += a0;
        float2 hv0 = h2[(size_t)s0 * 64 + j];
        acc.x = fmaf(hv0.x, a0, acc.x);
        acc.y = fmaf(hv0.y, a0, acc.y);
    }
    float inv = 1.f / (den + 1e-16f);
    float2 o;
    o.x = acc.x * inv + bias[2 * j];
    o.y = acc.y * inv + bias[2 * j + 1];
    if (RELU) { o.x = fmaxf(o.x, 0.f); o.y = fmaxf(o.y, 0.f); }
    ((float2*)out)[(size_t)w * 64 + j] = o;
}

__global__ void dst_agg40(const int* __restrict__ row_ptr, const int* __restrict__ src_sorted,
                          const float* __restrict__ als, const float* __restrict__ ald,
                          const float* __restrict__ hbuf, const float* __restrict__ bias,
                          float* __restrict__ out)
{
    int w = (blockIdx.x * blockDim.x + threadIdx.x) >> 6;
    if (w >= NN) return;
    int j = threadIdx.x & 63;
    float aldv = ald[w];
    int start = row_ptr[w], end = row_ptr[w + 1];
    float acc = 0.f, den = 0.f;
    int i = start;
    for (; i + 4 <= end; i += 4) {
        int s0 = src_sorted[i], s1 = src_sorted[i + 1], s2 = src_sorted[i + 2], s3 = src_sorted[i + 3];
        float e0 = als[s0] + aldv;
        float e1 = als[s1] + aldv;
        float e2 = als[s2] + aldv;
        float e3 = als[s3] + aldv;
        float hv0 = (j < 40) ? hbuf[(size_t)s0 * 40 + j] : 0.f;
        float hv1 = (j < 40) ? hbuf[(size_t)s1 * 40 + j] : 0.f;
        float hv2 = (j < 40) ? hbuf[(size_t)s2 * 40 + j] : 0.f;
        float hv3 = (j < 40) ? hbuf[(size_t)s3 * 40 + j] : 0.f;
        e0 = e0 > 0.f ? e0 : 0.2f * e0;
        e1 = e1 > 0.f ? e1 : 0.2f * e1;
        e2 = e2 > 0.f ? e2 : 0.2f * e2;
        e3 = e3 > 0.f ? e3 : 0.2f * e3;
        float a0 = __expf(e0), a1 = __expf(e1), a2 = __expf(e2), a3 = __expf(e3);
        den += (a0 + a1) + (a2 + a3);
        acc = fmaf(hv0, a0, acc);
        acc = fmaf(hv1, a1, acc);
        acc = fmaf(hv2, a2, acc);
        acc = fmaf(hv3, a3, acc);
    }
    for (; i < end; ++i) {
        int s0 = src_sorted[i];
        float e0 = als[s0] + aldv;
        e0 = e0 > 0.f ? e0 : 0.2f * e0;
        float a0 = __expf(e0);
        den += a0;
        if (j < 40) acc = fmaf(hbuf[(size_t)s0 * 40 + j], a0, acc);
    }
    if (j < 40) out[(size_t)w * 40 + j] = acc / (den + 1e-16f) + bias[j];
}

extern "C" void kernel_launch(void* const* d_in, const int* in_sizes, int n_in,
                              void* d_out, int out_size, void* d_ws, size_t ws_size,
                              hipStream_t stream) {
    const float* x   = (const float*)d_in[0];
    const int*   ei  = (const int*)d_in[1];
    const float* W0  = (const float*)d_in[2];
    const float* as0 = (const float*)d_in[3];
    const float* ad0 = (const float*)d_in[4];
    const float* b0  = (const float*)d_in[5];
    const float* W1  = (const float*)d_in[6];
    const float* as1 = (const float*)d_in[7];
    const float* ad1 = (const float*)d_in[8];
    const float* b1  = (const float*)d_in[9];
    const float* W2  = (const float*)d_in[10];
    const float* as2 = (const float*)d_in[11];
    const float* ad2 = (const float*)d_in[12];
    const float* b2  = (const float*)d_in[13];
    float* out = (float*)d_out;

    float* ws = (float*)d_ws;
    size_t off = 0;
    float* hbuf = ws + off; off += (size_t)NN * 128;
    float* fA   = ws + off; off += (size_t)NN * 128;
    float* fB   = ws + off; off += (size_t)NN * 128;
    float* als  = ws + off; off += (size_t)NN * 8;
    float* ald  = ws + off; off += (size_t)NN * 8;
    int* ibase      = (int*)(ws + off);
    int* cnt        = ibase; ibase += NN;
    int* excl       = ibase; ibase += NN;
    int* bsums      = ibase; ibase += 64;
    int* row_ptr    = ibase; ibase += NN + 1;
    int* cursor     = ibase; ibase += NN + 1;
    int* src_sorted = ibase; ibase += ETOT;

    const int TB = 256;
    const int EG = (ETOT + TB - 1) / TB;
    const int NSCAN = (NN + 1023) / 1024;

    // ---- CSR build (once; shared by all 3 layers) ----
    hipMemsetAsync(cnt, 0, (size_t)NN * sizeof(int), stream);
    k_hist<<<EG, TB, 0, stream>>>(ei, cnt);
    k_scan1<<<NSCAN, 1024, 0, stream>>>(cnt, excl, bsums);
    k_scan2<<<1, 64, 0, stream>>>(bsums, NSCAN);
    k_scan3<<<(NN + 1 + TB - 1) / TB, TB, 0, stream>>>(excl, bsums, row_ptr, cursor);
    k_scatter<<<EG, TB, 0, stream>>>(ei, cursor, src_sorted);

    const int GG128 = (NN + 31) / 32;               // 1563
    const int GG40  = NN / 16;                      // 3125 (exact)
    const int GAGG  = (NN * 64 + TB - 1) / TB;      // one wave per node

    // ---- Layer 0 ----
    gemm_att128<<<GG128, 256, 0, stream>>>(x, W0, as0, ad0, hbuf, als, ald);
    dst_agg128<true><<<GAGG, TB, 0, stream>>>(row_ptr, src_sorted, als, ald, hbuf, b0, fA);

    // ---- Layer 1 ----
    gemm_att128<<<GG128, 256, 0, stream>>>(fA, W1, as1, ad1, hbuf, als, ald);
    dst_agg128<true><<<GAGG, TB, 0, stream>>>(row_ptr, src_sorted, als, ald, hbuf, b1, fB);

    // ---- Layer 2 ----
    gemm_att40<<<GG40, 256, 0, stream>>>(fB, W2, as2, ad2, hbuf, als, ald);
    dst_agg40<<<GAGG, TB, 0, stream>>>(row_ptr, src_sorted, als, ald, hbuf, b2, out);
}

// Round 5
// 340.444 us; speedup vs baseline: 5.6349x; 1.1111x over previous
//
#include <hip/hip_runtime.h>

#define NN   50000
#define ERAW 800000
#define ETOT 850000

__device__ __forceinline__ void edge_sd(const int* __restrict__ ei, int e, int& s, int& d) {
    if (e < ERAW) { s = ei[e]; d = ei[ERAW + e]; }
    else { int n = e - ERAW; s = n; d = n; }
}

// bf16 pack/unpack (RNE), 2 elements per uint: low16 = a, high16 = b
__device__ __forceinline__ unsigned pack_bf16x2(float a, float b) {
    unsigned ua = __float_as_uint(a), ub = __float_as_uint(b);
    ua += 0x7fffu + ((ua >> 16) & 1u);
    ub += 0x7fffu + ((ub >> 16) & 1u);
    return (ua >> 16) | (ub & 0xffff0000u);
}
__device__ __forceinline__ float2 unpack_bf16x2(unsigned v) {
    float2 r;
    r.x = __uint_as_float(v << 16);
    r.y = __uint_as_float(v & 0xffff0000u);
    return r;
}

// ---------------- CSR build (by destination) ----------------
__global__ void k_hist(const int* __restrict__ ei, int* __restrict__ cnt) {
    int e = blockIdx.x * blockDim.x + threadIdx.x;
    if (e >= ETOT) return;
    int s, d; edge_sd(ei, e, s, d); (void)s;
    atomicAdd(&cnt[d], 1);
}

__global__ void k_scan1(const int* __restrict__ cnt, int* __restrict__ excl, int* __restrict__ bsums) {
    __shared__ int tmp[1024];
    int t = threadIdx.x, g = blockIdx.x * 1024 + t;
    int v = (g < NN) ? cnt[g] : 0;
    tmp[t] = v;
    __syncthreads();
    for (int off = 1; off < 1024; off <<= 1) {
        int u = (t >= off) ? tmp[t - off] : 0;
        __syncthreads();
        tmp[t] += u;
        __syncthreads();
    }
    if (g < NN) excl[g] = tmp[t] - v;
    if (t == 1023) bsums[blockIdx.x] = tmp[t];
}

__global__ void k_scan2(int* bsums, int nb) {
    if (threadIdx.x == 0 && blockIdx.x == 0) {
        int acc = 0;
        for (int i = 0; i < nb; ++i) { int v = bsums[i]; bsums[i] = acc; acc += v; }
    }
}

__global__ void k_scan3(const int* __restrict__ excl, const int* __restrict__ bsums,
                        int* __restrict__ row_ptr, int* __restrict__ cursor) {
    int g = blockIdx.x * blockDim.x + threadIdx.x;
    if (g > NN) return;
    int v = (g < NN) ? (excl[g] + bsums[g >> 10]) : ETOT;
    row_ptr[g] = v;
    if (g < NN) cursor[g] = v;
}

__global__ void k_scatter(const int* __restrict__ ei, int* __restrict__ cursor,
                          int* __restrict__ src_sorted) {
    int e = blockIdx.x * blockDim.x + threadIdx.x;
    if (e >= ETOT) return;
    int s, d; edge_sd(ei, e, s, d);
    int pos = atomicAdd(&cursor[d], 1);
    src_sorted[pos] = s;
}

// ---------------- GEMM + attention coefficients (layers 0/1: 128 -> 8x16) ----------------
// 256 threads; 32 nodes x 128 cols per block; each thread 4 nodes x 4 cols.
// Output h written as packed bf16 (row = 64 uints). als/ald computed from f32 acc.
#define FMA4(xc, wv, i) \
    acc[i][0] = fmaf(xc, wv.x, acc[i][0]); \
    acc[i][1] = fmaf(xc, wv.y, acc[i][1]); \
    acc[i][2] = fmaf(xc, wv.z, acc[i][2]); \
    acc[i][3] = fmaf(xc, wv.w, acc[i][3]);

__global__ __launch_bounds__(256) void gemm_att128(
    const float* __restrict__ x, const float* __restrict__ W,
    const float* __restrict__ asrc, const float* __restrict__ adst,
    unsigned* __restrict__ hb, float* __restrict__ als, float* __restrict__ ald)
{
    __shared__ float ws[32 * 128];
    __shared__ float xs[32 * 32];
    int t = threadIdx.x;
    int tx = t & 31, ty = t >> 5;      // cols 4tx..4tx+3, nodes 4ty..4ty+3
    int n0 = blockIdx.x * 32;

    float acc[4][4];
    #pragma unroll
    for (int i = 0; i < 4; ++i)
        #pragma unroll
        for (int j = 0; j < 4; ++j) acc[i][j] = 0.f;

    int ngx = n0 + (t >> 3); if (ngx >= NN) ngx = NN - 1;
    const float4* xrow = (const float4*)(x + (size_t)ngx * 128);
    int kcx = t & 7;

    for (int kt = 0; kt < 4; ++kt) {
        const float4* Wg = (const float4*)(W + (size_t)kt * 32 * 128);
        float4* ws4 = (float4*)ws;
        #pragma unroll
        for (int i = 0; i < 4; ++i) ws4[i * 256 + t] = Wg[i * 256 + t];
        ((float4*)xs)[t] = xrow[kt * 8 + kcx];
        __syncthreads();
        #pragma unroll
        for (int kc = 0; kc < 8; ++kc) {
            float4 wv0 = ((const float4*)(ws + (kc * 4 + 0) * 128))[tx];
            float4 wv1 = ((const float4*)(ws + (kc * 4 + 1) * 128))[tx];
            float4 wv2 = ((const float4*)(ws + (kc * 4 + 2) * 128))[tx];
            float4 wv3 = ((const float4*)(ws + (kc * 4 + 3) * 128))[tx];
            #pragma unroll
            for (int i = 0; i < 4; ++i) {
                float4 xv = ((const float4*)(xs + (4 * ty + i) * 32))[kc];
                FMA4(xv.x, wv0, i)
                FMA4(xv.y, wv1, i)
                FMA4(xv.z, wv2, i)
                FMA4(xv.w, wv3, i)
            }
        }
        __syncthreads();
    }

    float4 as4 = ((const float4*)asrc)[tx];
    float4 ad4 = ((const float4*)adst)[tx];
    int hd = tx >> 2;                    // head of cols 4tx..4tx+3 (C=16)
    #pragma unroll
    for (int i = 0; i < 4; ++i) {
        int n = n0 + 4 * ty + i;
        if (n < NN) {
            uint2 hp;
            hp.x = pack_bf16x2(acc[i][0], acc[i][1]);
            hp.y = pack_bf16x2(acc[i][2], acc[i][3]);
            ((uint2*)(hb + (size_t)n * 64))[tx] = hp;
            float v1 = acc[i][0] * as4.x + acc[i][1] * as4.y + acc[i][2] * as4.z + acc[i][3] * as4.w;
            float v2 = acc[i][0] * ad4.x + acc[i][1] * ad4.y + acc[i][2] * ad4.z + acc[i][3] * ad4.w;
            v1 += __shfl_xor(v1, 1); v1 += __shfl_xor(v1, 2);
            v2 += __shfl_xor(v2, 1); v2 += __shfl_xor(v2, 2);
            if ((tx & 3) == 0) { als[n * 8 + hd] = v1; ald[n * 8 + hd] = v2; }
        }
    }
}

// ---------------- GEMM + attention (layer 2: 128 -> 1x40, fp32 output) ----------------
__global__ __launch_bounds__(256) void gemm_att40(
    const float* __restrict__ x, const float* __restrict__ W,
    const float* __restrict__ asrc, const float* __restrict__ adst,
    float* __restrict__ h, float* __restrict__ als, float* __restrict__ ald)
{
    __shared__ float ws[128 * 40];
    __shared__ float xs[16 * 128];
    int t = threadIdx.x;
    int n0 = blockIdx.x * 16;
    #pragma unroll
    for (int i = 0; i < 5; ++i) ((float4*)ws)[i * 256 + t] = ((const float4*)W)[i * 256 + t];
    #pragma unroll
    for (int q = 0; q < 2; ++q) {
        int idx = q * 256 + t;
        int n = idx >> 5, kc = idx & 31;
        ((float4*)xs)[idx] = ((const float4*)(x + (size_t)(n0 + n) * 128))[kc];
    }
    __syncthreads();
    int w = t >> 6, c = t & 63;
    int cc = c < 40 ? c : 39;
    float acc[4] = {0.f, 0.f, 0.f, 0.f};
    #pragma unroll 4
    for (int kc = 0; kc < 32; ++kc) {
        float w0 = ws[(kc * 4 + 0) * 40 + cc];
        float w1 = ws[(kc * 4 + 1) * 40 + cc];
        float w2 = ws[(kc * 4 + 2) * 40 + cc];
        float w3 = ws[(kc * 4 + 3) * 40 + cc];
        #pragma unroll
        for (int i = 0; i < 4; ++i) {
            float4 xv = ((const float4*)(xs + (4 * w + i) * 128))[kc];
            acc[i] = fmaf(xv.x, w0, acc[i]);
            acc[i] = fmaf(xv.y, w1, acc[i]);
            acc[i] = fmaf(xv.z, w2, acc[i]);
            acc[i] = fmaf(xv.w, w3, acc[i]);
        }
    }
    float a_s = (c < 40) ? asrc[c] : 0.f;
    float a_d = (c < 40) ? adst[c] : 0.f;
    #pragma unroll
    for (int i = 0; i < 4; ++i) {
        int n = n0 + 4 * w + i;
        if (c < 40) h[(size_t)n * 40 + c] = acc[i];
        float v1 = acc[i] * a_s, v2 = acc[i] * a_d;
        #pragma unroll
        for (int m = 1; m < 64; m <<= 1) { v1 += __shfl_xor(v1, m); v2 += __shfl_xor(v2, m); }
        if (c == 0) { als[n] = v1; ald[n] = v2; }
    }
}

// ---------------- fused single-pass softmax + aggregate + finalize (bf16 h gather) ----------------
// One wave per dst node; lane j owns features 2j,2j+1 (head j>>3); one uint load per edge.
template<bool RELU>
__global__ void dst_agg128(const int* __restrict__ row_ptr, const int* __restrict__ src_sorted,
                           const float* __restrict__ als, const float* __restrict__ ald,
                           const unsigned* __restrict__ hb, const float* __restrict__ bias,
                           float* __restrict__ out)
{
    int w = (blockIdx.x * blockDim.x + threadIdx.x) >> 6;
    if (w >= NN) return;
    int j = threadIdx.x & 63;
    int myh = j >> 3;
    float aldv = ald[w * 8 + myh];
    int start = row_ptr[w], end = row_ptr[w + 1];
    float2 acc = make_float2(0.f, 0.f);
    float den = 0.f;
    int i = start;
    for (; i + 4 <= end; i += 4) {
        int s0 = src_sorted[i], s1 = src_sorted[i + 1], s2 = src_sorted[i + 2], s3 = src_sorted[i + 3];
        float e0 = als[s0 * 8 + myh] + aldv;
        float e1 = als[s1 * 8 + myh] + aldv;
        float e2 = als[s2 * 8 + myh] + aldv;
        float e3 = als[s3 * 8 + myh] + aldv;
        unsigned p0 = hb[(size_t)s0 * 64 + j];
        unsigned p1 = hb[(size_t)s1 * 64 + j];
        unsigned p2 = hb[(size_t)s2 * 64 + j];
        unsigned p3 = hb[(size_t)s3 * 64 + j];
        e0 = e0 > 0.f ? e0 : 0.2f * e0;
        e1 = e1 > 0.f ? e1 : 0.2f * e1;
        e2 = e2 > 0.f ? e2 : 0.2f * e2;
        e3 = e3 > 0.f ? e3 : 0.2f * e3;
        float a0 = __expf(e0), a1 = __expf(e1), a2 = __expf(e2), a3 = __expf(e3);
        den += (a0 + a1) + (a2 + a3);
        float2 h0 = unpack_bf16x2(p0), h1 = unpack_bf16x2(p1);
        float2 h2 = unpack_bf16x2(p2), h3 = unpack_bf16x2(p3);
        acc.x = fmaf(h0.x, a0, acc.x); acc.y = fmaf(h0.y, a0, acc.y);
        acc.x = fmaf(h1.x, a1, acc.x); acc.y = fmaf(h1.y, a1, acc.y);
        acc.x = fmaf(h2.x, a2, acc.x); acc.y = fmaf(h2.y, a2, acc.y);
        acc.x = fmaf(h3.x, a3, acc.x); acc.y = fmaf(h3.y, a3, acc.y);
    }
    for (; i < end; ++i) {
        int s0 = src_sorted[i];
        float e0 = als[s0 * 8 + myh] + aldv;
        e0 = e0 > 0.f ? e0 : 0.2f * e0;
        float a0 = __expf(e0);
        den += a0;
        float2 h0 = unpack_bf16x2(hb[(size_t)s0 * 64 + j]);
        acc.x = fmaf(h0.x, a0, acc.x);
        acc.y = fmaf(h0.y, a0, acc.y);
    }
    float inv = 1.f / (den + 1e-16f);
    float2 bv = ((const float2*)bias)[j];
    float2 o;
    o.x = acc.x * inv + bv.x;
    o.y = acc.y * inv + bv.y;
    if (RELU) { o.x = fmaxf(o.x, 0.f); o.y = fmaxf(o.y, 0.f); }
    ((float2*)out)[(size_t)w * 64 + j] = o;
}

__global__ void dst_agg40(const int* __restrict__ row_ptr, const int* __restrict__ src_sorted,
                          const float* __restrict__ als, const float* __restrict__ ald,
                          const float* __restrict__ hbuf, const float* __restrict__ bias,
                          float* __restrict__ out)
{
    int w = (blockIdx.x * blockDim.x + threadIdx.x) >> 6;
    if (w >= NN) return;
    int j = threadIdx.x & 63;
    float aldv = ald[w];
    int start = row_ptr[w], end = row_ptr[w + 1];
    float acc = 0.f, den = 0.f;
    int i = start;
    for (; i + 4 <= end; i += 4) {
        int s0 = src_sorted[i], s1 = src_sorted[i + 1], s2 = src_sorted[i + 2], s3 = src_sorted[i + 3];
        float e0 = als[s0] + aldv;
        float e1 = als[s1] + aldv;
        float e2 = als[s2] + aldv;
        float e3 = als[s3] + aldv;
        float hv0 = (j < 40) ? hbuf[(size_t)s0 * 40 + j] : 0.f;
        float hv1 = (j < 40) ? hbuf[(size_t)s1 * 40 + j] : 0.f;
        float hv2 = (j < 40) ? hbuf[(size_t)s2 * 40 + j] : 0.f;
        float hv3 = (j < 40) ? hbuf[(size_t)s3 * 40 + j] : 0.f;
        e0 = e0 > 0.f ? e0 : 0.2f * e0;
        e1 = e1 > 0.f ? e1 : 0.2f * e1;
        e2 = e2 > 0.f ? e2 : 0.2f * e2;
        e3 = e3 > 0.f ? e3 : 0.2f * e3;
        float a0 = __expf(e0), a1 = __expf(e1), a2 = __expf(e2), a3 = __expf(e3);
        den += (a0 + a1) + (a2 + a3);
        acc = fmaf(hv0, a0, acc);
        acc = fmaf(hv1, a1, acc);
        acc = fmaf(hv2, a2, acc);
        acc = fmaf(hv3, a3, acc);
    }
    for (; i < end; ++i) {
        int s0 = src_sorted[i];
        float e0 = als[s0] + aldv;
        e0 = e0 > 0.f ? e0 : 0.2f * e0;
        float a0 = __expf(e0);
        den += a0;
        if (j < 40) acc = fmaf(hbuf[(size_t)s0 * 40 + j], a0, acc);
    }
    if (j < 40) out[(size_t)w * 40 + j] = acc / (den + 1e-16f) + bias[j];
}

extern "C" void kernel_launch(void* const* d_in, const int* in_sizes, int n_in,
                              void* d_out, int out_size, void* d_ws, size_t ws_size,
                              hipStream_t stream) {
    const float* x   = (const float*)d_in[0];
    const int*   ei  = (const int*)d_in[1];
    const float* W0  = (const float*)d_in[2];
    const float* as0 = (const float*)d_in[3];
    const float* ad0 = (const float*)d_in[4];
    const float* b0  = (const float*)d_in[5];
    const float* W1  = (const float*)d_in[6];
    const float* as1 = (const float*)d_in[7];
    const float* ad1 = (const float*)d_in[8];
    const float* b1  = (const float*)d_in[9];
    const float* W2  = (const float*)d_in[10];
    const float* as2 = (const float*)d_in[11];
    const float* ad2 = (const float*)d_in[12];
    const float* b2  = (const float*)d_in[13];
    float* out = (float*)d_out;

    float* ws = (float*)d_ws;
    size_t off = 0;
    unsigned* hb = (unsigned*)(ws + off); off += (size_t)NN * 64;  // bf16 h, layers 0/1
    float* fA   = ws + off; off += (size_t)NN * 128;
    float* fB   = ws + off; off += (size_t)NN * 128;
    float* h40  = ws + off; off += (size_t)NN * 40;
    float* als  = ws + off; off += (size_t)NN * 8;
    float* ald  = ws + off; off += (size_t)NN * 8;
    int* ibase      = (int*)(ws + off);
    int* cnt        = ibase; ibase += NN;
    int* excl       = ibase; ibase += NN;
    int* bsums      = ibase; ibase += 64;
    int* row_ptr    = ibase; ibase += NN + 1;
    int* cursor     = ibase; ibase += NN + 1;
    int* src_sorted = ibase; ibase += ETOT;

    const int TB = 256;
    const int EG = (ETOT + TB - 1) / TB;
    const int NSCAN = (NN + 1023) / 1024;

    // ---- CSR build (once; shared by all 3 layers) ----
    hipMemsetAsync(cnt, 0, (size_t)NN * sizeof(int), stream);
    k_hist<<<EG, TB, 0, stream>>>(ei, cnt);
    k_scan1<<<NSCAN, 1024, 0, stream>>>(cnt, excl, bsums);
    k_scan2<<<1, 64, 0, stream>>>(bsums, NSCAN);
    k_scan3<<<(NN + 1 + TB - 1) / TB, TB, 0, stream>>>(excl, bsums, row_ptr, cursor);
    k_scatter<<<EG, TB, 0, stream>>>(ei, cursor, src_sorted);

    const int GG128 = (NN + 31) / 32;               // 1563
    const int GG40  = NN / 16;                      // 3125 (exact)
    const int GAGG  = (NN * 64 + TB - 1) / TB;      // one wave per node

    // ---- Layer 0 ----
    gemm_att128<<<GG128, 256, 0, stream>>>(x, W0, as0, ad0, hb, als, ald);
    dst_agg128<true><<<GAGG, TB, 0, stream>>>(row_ptr, src_sorted, als, ald, hb, b0, fA);

    // ---- Layer 1 ----
    gemm_att128<<<GG128, 256, 0, stream>>>(fA, W1, as1, ad1, hb, als, ald);
    dst_agg128<true><<<GAGG, TB, 0, stream>>>(row_ptr, src_sorted, als, ald, hb, b1, fB);

    // ---- Layer 2 (fp32 throughout: direct output) ----
    gemm_att40<<<GG40, 256, 0, stream>>>(fB, W2, as2, ad2, h40, als, ald);
    dst_agg40<<<GAGG, TB, 0, stream>>>(row_ptr, src_sorted, als, ald, h40, b2, out);
}

// Round 6
// 298.120 us; speedup vs baseline: 6.4348x; 1.1420x over previous
//
#include <hip/hip_runtime.h>

#define NN    50000
#define ERAW  800000
#define ETOT  850000
#define NBUCK 782            // ceil(NN/64) buckets of 64 dst nodes
#define EPB_A 8192           // edges per block in bucketing passes
#define NBLK_A ((ETOT + EPB_A - 1) / EPB_A)   // 104
#define NCNT  (NBUCK * 64)   // 50048 (padded per-dst count array)

__device__ __forceinline__ void edge_sd(const int* __restrict__ ei, int e, int& s, int& d) {
    if (e < ERAW) { s = ei[e]; d = ei[ERAW + e]; }
    else { int n = e - ERAW; s = n; d = n; }
}

// bf16 pack/unpack (RNE), 2 elements per uint: low16 = a, high16 = b
__device__ __forceinline__ unsigned pack_bf16x2(float a, float b) {
    unsigned ua = __float_as_uint(a), ub = __float_as_uint(b);
    ua += 0x7fffu + ((ua >> 16) & 1u);
    ub += 0x7fffu + ((ub >> 16) & 1u);
    return (ua >> 16) | (ub & 0xffff0000u);
}
__device__ __forceinline__ float2 unpack_bf16x2(unsigned v) {
    float2 r;
    r.x = __uint_as_float(v << 16);
    r.y = __uint_as_float(v & 0xffff0000u);
    return r;
}

// ---------------- CSR build: two-level bucketed counting sort ----------------
// A1: per-block LDS histogram of coarse buckets -> global bucket counts
__global__ __launch_bounds__(256) void kA1(const int* __restrict__ ei, int* __restrict__ bucket_cnt) {
    __shared__ int lb[NBUCK];
    int t = threadIdx.x;
    for (int i = t; i < NBUCK; i += 256) lb[i] = 0;
    __syncthreads();
    int base = blockIdx.x * EPB_A;
    #pragma unroll 4
    for (int k = 0; k < EPB_A / 256; ++k) {
        int e = base + k * 256 + t;
        if (e < ETOT) {
            int s, d; edge_sd(ei, e, s, d); (void)s;
            atomicAdd(&lb[d >> 6], 1);
        }
    }
    __syncthreads();
    for (int i = t; i < NBUCK; i += 256) if (lb[i]) atomicAdd(&bucket_cnt[i], lb[i]);
}

// A2: exclusive scan of bucket counts (single block, 1024 threads)
__global__ void kA2(const int* __restrict__ bucket_cnt, int* __restrict__ bucket_off,
                    int* __restrict__ bucket_cur) {
    __shared__ int tmp[1024];
    int t = threadIdx.x;
    int v = (t < NBUCK) ? bucket_cnt[t] : 0;
    tmp[t] = v;
    __syncthreads();
    for (int off = 1; off < 1024; off <<= 1) {
        int u = (t >= off) ? tmp[t - off] : 0;
        __syncthreads();
        tmp[t] += u;
        __syncthreads();
    }
    if (t < NBUCK) { int ex = tmp[t] - v; bucket_off[t] = ex; bucket_cur[t] = ex; }
    if (t == 0) bucket_off[NBUCK] = ETOT;
}

// A3: scatter edges into bucket regions (packed (dst<<16)|src). Per-block LDS hist ->
// one global atomic per (block,bucket) reserves a contiguous run -> clustered writes.
__global__ __launch_bounds__(256) void kA3(const int* __restrict__ ei, int* __restrict__ bucket_cur,
                                           unsigned* __restrict__ ebkt) {
    __shared__ int lb[NBUCK];
    int t = threadIdx.x;
    for (int i = t; i < NBUCK; i += 256) lb[i] = 0;
    __syncthreads();
    int base = blockIdx.x * EPB_A;
    #pragma unroll 4
    for (int k = 0; k < EPB_A / 256; ++k) {
        int e = base + k * 256 + t;
        if (e < ETOT) {
            int s, d; edge_sd(ei, e, s, d); (void)s;
            atomicAdd(&lb[d >> 6], 1);
        }
    }
    __syncthreads();
    for (int i = t; i < NBUCK; i += 256) {
        int c = lb[i];
        lb[i] = c ? atomicAdd(&bucket_cur[i], c) : 0;
    }
    __syncthreads();
    #pragma unroll 4
    for (int k = 0; k < EPB_A / 256; ++k) {
        int e = base + k * 256 + t;
        if (e < ETOT) {
            int s, d; edge_sd(ei, e, s, d);
            int pos = atomicAdd(&lb[d >> 6], 1);
            ebkt[pos] = ((unsigned)d << 16) | (unsigned)s;
        }
    }
}

// B1: per-dst counts, one block per bucket (LDS counters, no global atomics)
__global__ __launch_bounds__(256) void kB1(const int* __restrict__ bucket_off,
                                           const unsigned* __restrict__ ebkt, int* __restrict__ cnt) {
    __shared__ int lc[64];
    int b = blockIdx.x, t = threadIdx.x;
    if (t < 64) lc[t] = 0;
    __syncthreads();
    int s0 = bucket_off[b], s1 = bucket_off[b + 1];
    for (int i = s0 + t; i < s1; i += 256) atomicAdd(&lc[(ebkt[i] >> 16) & 63], 1);
    __syncthreads();
    if (t < 64) cnt[b * 64 + t] = lc[t];
}

// generic scan over n elements (n <= 1024*blocks)
__global__ void k_scan1(const int* __restrict__ cnt, int* __restrict__ excl,
                        int* __restrict__ bsums, int n) {
    __shared__ int tmp[1024];
    int t = threadIdx.x, g = blockIdx.x * 1024 + t;
    int v = (g < n) ? cnt[g] : 0;
    tmp[t] = v;
    __syncthreads();
    for (int off = 1; off < 1024; off <<= 1) {
        int u = (t >= off) ? tmp[t - off] : 0;
        __syncthreads();
        tmp[t] += u;
        __syncthreads();
    }
    if (g < n) excl[g] = tmp[t] - v;
    if (t == 1023) bsums[blockIdx.x] = tmp[t];
}

__global__ void k_scan2(int* bsums, int nb) {
    if (threadIdx.x == 0 && blockIdx.x == 0) {
        int acc = 0;
        for (int i = 0; i < nb; ++i) { int v = bsums[i]; bsums[i] = acc; acc += v; }
    }
}

__global__ void k_scan3(const int* __restrict__ excl, const int* __restrict__ bsums,
                        int* __restrict__ row_ptr, int n) {
    int g = blockIdx.x * blockDim.x + threadIdx.x;
    if (g > n) return;
    row_ptr[g] = (g < n) ? (excl[g] + bsums[g >> 10]) : ETOT;
}

// B3: final within-bucket scatter; all writes land in the bucket's private window
__global__ __launch_bounds__(256) void kB3(const int* __restrict__ bucket_off,
                                           const unsigned* __restrict__ ebkt,
                                           const int* __restrict__ row_ptr,
                                           int* __restrict__ src_sorted) {
    __shared__ int lcur[64];
    int b = blockIdx.x, t = threadIdx.x;
    if (t < 64) lcur[t] = row_ptr[b * 64 + t];
    __syncthreads();
    int s0 = bucket_off[b], s1 = bucket_off[b + 1];
    for (int i = s0 + t; i < s1; i += 256) {
        unsigned k = ebkt[i];
        int pos = atomicAdd(&lcur[(k >> 16) & 63], 1);
        src_sorted[pos] = (int)(k & 0xffffu);
    }
}

// ---------------- GEMM + attention coefficients (layers 0/1: 128 -> 8x16) ----------------
#define FMA4(xc, wv, i) \
    acc[i][0] = fmaf(xc, wv.x, acc[i][0]); \
    acc[i][1] = fmaf(xc, wv.y, acc[i][1]); \
    acc[i][2] = fmaf(xc, wv.z, acc[i][2]); \
    acc[i][3] = fmaf(xc, wv.w, acc[i][3]);

__global__ __launch_bounds__(256) void gemm_att128(
    const float* __restrict__ x, const float* __restrict__ W,
    const float* __restrict__ asrc, const float* __restrict__ adst,
    unsigned* __restrict__ hb, float* __restrict__ als, float* __restrict__ ald)
{
    __shared__ float ws[32 * 128];
    __shared__ float xs[32 * 32];
    int t = threadIdx.x;
    int tx = t & 31, ty = t >> 5;
    int n0 = blockIdx.x * 32;

    float acc[4][4];
    #pragma unroll
    for (int i = 0; i < 4; ++i)
        #pragma unroll
        for (int j = 0; j < 4; ++j) acc[i][j] = 0.f;

    int ngx = n0 + (t >> 3); if (ngx >= NN) ngx = NN - 1;
    const float4* xrow = (const float4*)(x + (size_t)ngx * 128);
    int kcx = t & 7;

    for (int kt = 0; kt < 4; ++kt) {
        const float4* Wg = (const float4*)(W + (size_t)kt * 32 * 128);
        float4* ws4 = (float4*)ws;
        #pragma unroll
        for (int i = 0; i < 4; ++i) ws4[i * 256 + t] = Wg[i * 256 + t];
        ((float4*)xs)[t] = xrow[kt * 8 + kcx];
        __syncthreads();
        #pragma unroll
        for (int kc = 0; kc < 8; ++kc) {
            float4 wv0 = ((const float4*)(ws + (kc * 4 + 0) * 128))[tx];
            float4 wv1 = ((const float4*)(ws + (kc * 4 + 1) * 128))[tx];
            float4 wv2 = ((const float4*)(ws + (kc * 4 + 2) * 128))[tx];
            float4 wv3 = ((const float4*)(ws + (kc * 4 + 3) * 128))[tx];
            #pragma unroll
            for (int i = 0; i < 4; ++i) {
                float4 xv = ((const float4*)(xs + (4 * ty + i) * 32))[kc];
                FMA4(xv.x, wv0, i)
                FMA4(xv.y, wv1, i)
                FMA4(xv.z, wv2, i)
                FMA4(xv.w, wv3, i)
            }
        }
        __syncthreads();
    }

    float4 as4 = ((const float4*)asrc)[tx];
    float4 ad4 = ((const float4*)adst)[tx];
    int hd = tx >> 2;
    #pragma unroll
    for (int i = 0; i < 4; ++i) {
        int n = n0 + 4 * ty + i;
        if (n < NN) {
            uint2 hp;
            hp.x = pack_bf16x2(acc[i][0], acc[i][1]);
            hp.y = pack_bf16x2(acc[i][2], acc[i][3]);
            ((uint2*)(hb + (size_t)n * 64))[tx] = hp;
            float v1 = acc[i][0] * as4.x + acc[i][1] * as4.y + acc[i][2] * as4.z + acc[i][3] * as4.w;
            float v2 = acc[i][0] * ad4.x + acc[i][1] * ad4.y + acc[i][2] * ad4.z + acc[i][3] * ad4.w;
            v1 += __shfl_xor(v1, 1); v1 += __shfl_xor(v1, 2);
            v2 += __shfl_xor(v2, 1); v2 += __shfl_xor(v2, 2);
            if ((tx & 3) == 0) { als[n * 8 + hd] = v1; ald[n * 8 + hd] = v2; }
        }
    }
}

// ---------------- GEMM + attention (layer 2: 128 -> 1x40, fp32 output) ----------------
__global__ __launch_bounds__(256) void gemm_att40(
    const float* __restrict__ x, const float* __restrict__ W,
    const float* __restrict__ asrc, const float* __restrict__ adst,
    float* __restrict__ h, float* __restrict__ als, float* __restrict__ ald)
{
    __shared__ float ws[128 * 40];
    __shared__ float xs[16 * 128];
    int t = threadIdx.x;
    int n0 = blockIdx.x * 16;
    #pragma unroll
    for (int i = 0; i < 5; ++i) ((float4*)ws)[i * 256 + t] = ((const float4*)W)[i * 256 + t];
    #pragma unroll
    for (int q = 0; q < 2; ++q) {
        int idx = q * 256 + t;
        int n = idx >> 5, kc = idx & 31;
        ((float4*)xs)[idx] = ((const float4*)(x + (size_t)(n0 + n) * 128))[kc];
    }
    __syncthreads();
    int w = t >> 6, c = t & 63;
    int cc = c < 40 ? c : 39;
    float acc[4] = {0.f, 0.f, 0.f, 0.f};
    #pragma unroll 4
    for (int kc = 0; kc < 32; ++kc) {
        float w0 = ws[(kc * 4 + 0) * 40 + cc];
        float w1 = ws[(kc * 4 + 1) * 40 + cc];
        float w2 = ws[(kc * 4 + 2) * 40 + cc];
        float w3 = ws[(kc * 4 + 3) * 40 + cc];
        #pragma unroll
        for (int i = 0; i < 4; ++i) {
            float4 xv = ((const float4*)(xs + (4 * w + i) * 128))[kc];
            acc[i] = fmaf(xv.x, w0, acc[i]);
            acc[i] = fmaf(xv.y, w1, acc[i]);
            acc[i] = fmaf(xv.z, w2, acc[i]);
            acc[i] = fmaf(xv.w, w3, acc[i]);
        }
    }
    float a_s = (c < 40) ? asrc[c] : 0.f;
    float a_d = (c < 40) ? adst[c] : 0.f;
    #pragma unroll
    for (int i = 0; i < 4; ++i) {
        int n = n0 + 4 * w + i;
        if (c < 40) h[(size_t)n * 40 + c] = acc[i];
        float v1 = acc[i] * a_s, v2 = acc[i] * a_d;
        #pragma unroll
        for (int m = 1; m < 64; m <<= 1) { v1 += __shfl_xor(v1, m); v2 += __shfl_xor(v2, m); }
        if (c == 0) { als[n] = v1; ald[n] = v2; }
    }
}

// ---------------- fused single-pass softmax + aggregate + finalize (bf16 h gather) ----------------
template<bool RELU>
__global__ void dst_agg128(const int* __restrict__ row_ptr, const int* __restrict__ src_sorted,
                           const float* __restrict__ als, const float* __restrict__ ald,
                           const unsigned* __restrict__ hb, const float* __restrict__ bias,
                           float* __restrict__ out)
{
    int w = (blockIdx.x * blockDim.x + threadIdx.x) >> 6;
    if (w >= NN) return;
    int j = threadIdx.x & 63;
    int myh = j >> 3;
    float aldv = ald[w * 8 + myh];
    int start = row_ptr[w], end = row_ptr[w + 1];
    float2 acc = make_float2(0.f, 0.f);
    float den = 0.f;
    int i = start;
    for (; i + 4 <= end; i += 4) {
        int s0 = src_sorted[i], s1 = src_sorted[i + 1], s2 = src_sorted[i + 2], s3 = src_sorted[i + 3];
        float e0 = als[s0 * 8 + myh] + aldv;
        float e1 = als[s1 * 8 + myh] + aldv;
        float e2 = als[s2 * 8 + myh] + aldv;
        float e3 = als[s3 * 8 + myh] + aldv;
        unsigned p0 = hb[(size_t)s0 * 64 + j];
        unsigned p1 = hb[(size_t)s1 * 64 + j];
        unsigned p2 = hb[(size_t)s2 * 64 + j];
        unsigned p3 = hb[(size_t)s3 * 64 + j];
        e0 = e0 > 0.f ? e0 : 0.2f * e0;
        e1 = e1 > 0.f ? e1 : 0.2f * e1;
        e2 = e2 > 0.f ? e2 : 0.2f * e2;
        e3 = e3 > 0.f ? e3 : 0.2f * e3;
        float a0 = __expf(e0), a1 = __expf(e1), a2 = __expf(e2), a3 = __expf(e3);
        den += (a0 + a1) + (a2 + a3);
        float2 h0 = unpack_bf16x2(p0), h1 = unpack_bf16x2(p1);
        float2 h2 = unpack_bf16x2(p2), h3 = unpack_bf16x2(p3);
        acc.x = fmaf(h0.x, a0, acc.x); acc.y = fmaf(h0.y, a0, acc.y);
        acc.x = fmaf(h1.x, a1, acc.x); acc.y = fmaf(h1.y, a1, acc.y);
        acc.x = fmaf(h2.x, a2, acc.x); acc.y = fmaf(h2.y, a2, acc.y);
        acc.x = fmaf(h3.x, a3, acc.x); acc.y = fmaf(h3.y, a3, acc.y);
    }
    for (; i < end; ++i) {
        int s0 = src_sorted[i];
        float e0 = als[s0 * 8 + myh] + aldv;
        e0 = e0 > 0.f ? e0 : 0.2f * e0;
        float a0 = __expf(e0);
        den += a0;
        float2 h0 = unpack_bf16x2(hb[(size_t)s0 * 64 + j]);
        acc.x = fmaf(h0.x, a0, acc.x);
        acc.y = fmaf(h0.y, a0, acc.y);
    }
    float inv = 1.f / (den + 1e-16f);
    float2 bv = ((const float2*)bias)[j];
    float2 o;
    o.x = acc.x * inv + bv.x;
    o.y = acc.y * inv + bv.y;
    if (RELU) { o.x = fmaxf(o.x, 0.f); o.y = fmaxf(o.y, 0.f); }
    ((float2*)out)[(size_t)w * 64 + j] = o;
}

__global__ void dst_agg40(const int* __restrict__ row_ptr, const int* __restrict__ src_sorted,
                          const float* __restrict__ als, const float* __restrict__ ald,
                          const float* __restrict__ hbuf, const float* __restrict__ bias,
                          float* __restrict__ out)
{
    int w = (blockIdx.x * blockDim.x + threadIdx.x) >> 6;
    if (w >= NN) return;
    int j = threadIdx.x & 63;
    float aldv = ald[w];
    int start = row_ptr[w], end = row_ptr[w + 1];
    float acc = 0.f, den = 0.f;
    int i = start;
    for (; i + 4 <= end; i += 4) {
        int s0 = src_sorted[i], s1 = src_sorted[i + 1], s2 = src_sorted[i + 2], s3 = src_sorted[i + 3];
        float e0 = als[s0] + aldv;
        float e1 = als[s1] + aldv;
        float e2 = als[s2] + aldv;
        float e3 = als[s3] + aldv;
        float hv0 = (j < 40) ? hbuf[(size_t)s0 * 40 + j] : 0.f;
        float hv1 = (j < 40) ? hbuf[(size_t)s1 * 40 + j] : 0.f;
        float hv2 = (j < 40) ? hbuf[(size_t)s2 * 40 + j] : 0.f;
        float hv3 = (j < 40) ? hbuf[(size_t)s3 * 40 + j] : 0.f;
        e0 = e0 > 0.f ? e0 : 0.2f * e0;
        e1 = e1 > 0.f ? e1 : 0.2f * e1;
        e2 = e2 > 0.f ? e2 : 0.2f * e2;
        e3 = e3 > 0.f ? e3 : 0.2f * e3;
        float a0 = __expf(e0), a1 = __expf(e1), a2 = __expf(e2), a3 = __expf(e3);
        den += (a0 + a1) + (a2 + a3);
        acc = fmaf(hv0, a0, acc);
        acc = fmaf(hv1, a1, acc);
        acc = fmaf(hv2, a2, acc);
        acc = fmaf(hv3, a3, acc);
    }
    for (; i < end; ++i) {
        int s0 = src_sorted[i];
        float e0 = als[s0] + aldv;
        e0 = e0 > 0.f ? e0 : 0.2f * e0;
        float a0 = __expf(e0);
        den += a0;
        if (j < 40) acc = fmaf(hbuf[(size_t)s0 * 40 + j], a0, acc);
    }
    if (j < 40) out[(size_t)w * 40 + j] = acc / (den + 1e-16f) + bias[j];
}

extern "C" void kernel_launch(void* const* d_in, const int* in_sizes, int n_in,
                              void* d_out, int out_size, void* d_ws, size_t ws_size,
                              hipStream_t stream) {
    const float* x   = (const float*)d_in[0];
    const int*   ei  = (const int*)d_in[1];
    const float* W0  = (const float*)d_in[2];
    const float* as0 = (const float*)d_in[3];
    const float* ad0 = (const float*)d_in[4];
    const float* b0  = (const float*)d_in[5];
    const float* W1  = (const float*)d_in[6];
    const float* as1 = (const float*)d_in[7];
    const float* ad1 = (const float*)d_in[8];
    const float* b1  = (const float*)d_in[9];
    const float* W2  = (const float*)d_in[10];
    const float* as2 = (const float*)d_in[11];
    const float* ad2 = (const float*)d_in[12];
    const float* b2  = (const float*)d_in[13];
    float* out = (float*)d_out;

    float* ws = (float*)d_ws;
    size_t off = 0;
    unsigned* hb = (unsigned*)(ws + off); off += (size_t)NN * 64;  // bf16 h, layers 0/1
    float* fA   = ws + off; off += (size_t)NN * 128;
    float* fB   = ws + off; off += (size_t)NN * 128;
    float* h40  = ws + off; off += (size_t)NN * 40;
    float* als  = ws + off; off += (size_t)NN * 8;
    float* ald  = ws + off; off += (size_t)NN * 8;
    int* ibase       = (int*)(ws + off);
    int* bucket_cnt  = ibase; ibase += NBUCK;
    int* bucket_off  = ibase; ibase += NBUCK + 2;
    int* bucket_cur  = ibase; ibase += NBUCK;
    int* cnt         = ibase; ibase += NCNT;
    int* excl        = ibase; ibase += NCNT;
    int* bsums       = ibase; ibase += 64;
    int* row_ptr     = ibase; ibase += NCNT + 1;
    unsigned* ebkt   = (unsigned*)ibase; ibase += ETOT;
    int* src_sorted  = ibase; ibase += ETOT;

    const int TB = 256;
    const int NSCAN = (NCNT + 1023) / 1024;   // 49

    // ---- CSR build (bucketed counting sort; shared by all 3 layers) ----
    hipMemsetAsync(bucket_cnt, 0, NBUCK * sizeof(int), stream);
    kA1<<<NBLK_A, 256, 0, stream>>>(ei, bucket_cnt);
    kA2<<<1, 1024, 0, stream>>>(bucket_cnt, bucket_off, bucket_cur);
    kA3<<<NBLK_A, 256, 0, stream>>>(ei, bucket_cur, ebkt);
    kB1<<<NBUCK, 256, 0, stream>>>(bucket_off, ebkt, cnt);
    k_scan1<<<NSCAN, 1024, 0, stream>>>(cnt, excl, bsums, NCNT);
    k_scan2<<<1, 64, 0, stream>>>(bsums, NSCAN);
    k_scan3<<<(NCNT + 1 + TB - 1) / TB, TB, 0, stream>>>(excl, bsums, row_ptr, NCNT);
    kB3<<<NBUCK, 256, 0, stream>>>(bucket_off, ebkt, row_ptr, src_sorted);

    const int GG128 = (NN + 31) / 32;               // 1563
    const int GG40  = NN / 16;                      // 3125 (exact)
    const int GAGG  = (NN * 64 + TB - 1) / TB;      // one wave per node

    // ---- Layer 0 ----
    gemm_att128<<<GG128, 256, 0, stream>>>(x, W0, as0, ad0, hb, als, ald);
    dst_agg128<true><<<GAGG, TB, 0, stream>>>(row_ptr, src_sorted, als, ald, hb, b0, fA);

    // ---- Layer 1 ----
    gemm_att128<<<GG128, 256, 0, stream>>>(fA, W1, as1, ad1, hb, als, ald);
    dst_agg128<true><<<GAGG, TB, 0, stream>>>(row_ptr, src_sorted, als, ald, hb, b1, fB);

    // ---- Layer 2 (fp32 throughout: direct output) ----
    gemm_att40<<<GG40, 256, 0, stream>>>(fB, W2, as2, ad2, h40, als, ald);
    dst_agg40<<<GAGG, TB, 0, stream>>>(row_ptr, src_sorted, als, ald, h40, b2, out);
}